// Round 8
// baseline (43.952 us; speedup 1.0000x reference)
//
#include <hip/hip_runtime.h>
#include <math.h>

#define B_DIM 4096
#define L_DIM 512
#define N_DIM 1024

// -half*log(2): exact value of each term once P has fully underflowed to zero.
#define NEG_HALF_LOG2 (-0.34657359027997264f)

typedef float f32x2 __attribute__((ext_vector_type(2)));
typedef float f32x4 __attribute__((ext_vector_type(4)));
#define VLO(v) __builtin_shufflevector(v, v, 0, 1)
#define VHI(v) __builtin_shufflevector(v, v, 2, 3)

// ---------------------------------------------------------------------------
// Packed fp32 ops (VOP3P), 2x the scalar v_fma_f32 rate on CDNA4.
// ---------------------------------------------------------------------------
__device__ __forceinline__ f32x2 pk_fma(f32x2 a, f32x2 b, f32x2 c) {
    f32x2 d;
    asm("v_pk_fma_f32 %0, %1, %2, %3" : "=v"(d) : "v"(a), "v"(b), "v"(c));
    return d;
}
__device__ __forceinline__ f32x2 pk_mul(f32x2 a, f32x2 b) {
    f32x2 d;
    asm("v_pk_mul_f32 %0, %1, %2" : "=v"(d) : "v"(a), "v"(b));
    return d;
}
__device__ __forceinline__ f32x2 pk_add(f32x2 a, f32x2 b) {
    f32x2 d;
    asm("v_pk_add_f32 %0, %1, %2" : "=v"(d) : "v"(a), "v"(b));
    return d;
}

// ---------------------------------------------------------------------------
// Kernel A: transpose eps (2, N, L) -> epsT (L, 2, N).
// ---------------------------------------------------------------------------
__global__ void transpose_eps(const float* __restrict__ eps,
                              float* __restrict__ epsT) {
    __shared__ float tile[32][33];
    const int s  = blockIdx.z;
    const int i0 = blockIdx.x * 32;
    const int n0 = blockIdx.y * 32;
    const int tx = threadIdx.x;
    const int ty = threadIdx.y;
#pragma unroll
    for (int k = 0; k < 32; k += 8) {
        tile[ty + k][tx] =
            eps[((size_t)s * N_DIM + (size_t)(n0 + ty + k)) * L_DIM + (i0 + tx)];
    }
    __syncthreads();
#pragma unroll
    for (int k = 0; k < 32; k += 8) {
        epsT[(size_t)(i0 + ty + k) * (2 * N_DIM) + (size_t)s * N_DIM + (n0 + tx)] =
            tile[tx][ty + k];
    }
}

// ---------------------------------------------------------------------------
// DPP wave-64 sum; lane 63 ends with the full sum. All VALU-pipe.
// ---------------------------------------------------------------------------
template <int CTRL>
__device__ __forceinline__ float dpp_add(float x) {
    int v = __builtin_amdgcn_update_dpp(0, __float_as_int(x), CTRL, 0xf, 0xf, true);
    return x + __int_as_float(v);
}
__device__ __forceinline__ float wave_sum63(float x) {
    x = dpp_add<0x111>(x);  // row_shr:1
    x = dpp_add<0x112>(x);  // row_shr:2
    x = dpp_add<0x114>(x);  // row_shr:4
    x = dpp_add<0x118>(x);  // row_shr:8
    x = dpp_add<0x142>(x);  // row_bcast:15
    x = dpp_add<0x143>(x);  // row_bcast:31
    return x;
}
__device__ __forceinline__ float read63(float x) {
    return __int_as_float(__builtin_amdgcn_readlane(__float_as_int(x), 63));
}

// ---------------------------------------------------------------------------
// Main kernel (LDS-staged): 512-thread block = 8 waves, each wave owns 2 rows
// -> 16 rows/block, grid 256 = 1 block/CU. Per step the 8 KB eps slice is
// staged ONCE per block into a double-buffered LDS tile (each thread carries
// one f32x4), cutting L1/L2 traffic 8x vs per-wave reads. T14 split: issue
// next-slice global load at step top, compute current step from LDS, ds_write
// the staged data, one barrier per step. Block-wide early-exit vote per
// 8-step chunk (dead rows contribute exactly -1/2*log2 -> overshoot exact).
// ---------------------------------------------------------------------------
__global__ __launch_bounds__(512, 2) void arqgps_lds(
    const int* __restrict__ indices,
    const float* __restrict__ epsT,   // (L, 2, N)
    float* __restrict__ out)
{
    const int tid   = threadIdx.x;
    const int lane  = tid & 63;
    const int wave  = __builtin_amdgcn_readfirstlane(tid >> 6);
    const int b0    = blockIdx.x * 16 + wave * 2;
    const int b1    = b0 + 1;
    const int lane4 = lane * 4;
    const int* idx0 = indices + (size_t)b0 * L_DIM;
    const int* idx1 = indices + (size_t)b1 * L_DIM;

    __shared__ float sbuf[2][2 * N_DIM];   // 2 x 8 KB double buffer

    // Prime: stage slice 0 into buffer 0.
    *(f32x4*)(&sbuf[0][tid * 4]) = *(const f32x4*)(epsT + tid * 4);
    __syncthreads();

    f32x2 P0[8], P1[8];
#pragma unroll
    for (int c = 0; c < 8; ++c) {
        P0[c] = (f32x2){1.0f, 1.0f};
        P1[c] = (f32x2){1.0f, 1.0f};
    }

    float vacc = 0.0f;   // batched-tail accumulator (lanes 0..15 live)
    float uacc = 0.0f;   // uniform early-exit remainder
    float collA = 0.0f, collB = 0.0f;

    for (int i0 = 0; i0 < L_DIM; i0 += 8) {
        const int4 sA0 = *(const int4*)(idx0 + i0);
        const int4 sB0 = *(const int4*)(idx0 + i0 + 4);
        const int4 sA1 = *(const int4*)(idx1 + i0);
        const int4 sB1 = *(const int4*)(idx1 + i0 + 4);
        int smask0 = 0, smask1 = 0;
#pragma unroll
        for (int k = 0; k < 8; ++k) {
            const int i   = i0 + k;
            const int cur = i & 1;

            // Issue next-slice global load (latency hidden under compute).
            const int inext = (i + 1 < L_DIM) ? (i + 1) : (L_DIM - 1);
            const f32x4 stg =
                *(const f32x4*)(epsT + (size_t)inext * (2 * N_DIM) + tid * 4);

            // Read this step's slice from LDS.
            const float* e = &sbuf[cur][0];
            f32x4 e0q[4], e1q[4];
#pragma unroll
            for (int c = 0; c < 4; ++c) {
                e0q[c] = *(const f32x4*)(e + c * 256 + lane4);
                e1q[c] = *(const f32x4*)(e + N_DIM + c * 256 + lane4);
            }

            // Row 0 dots.
            f32x2 a00 = {0.f, 0.f}, a01 = {0.f, 0.f};
            f32x2 a10 = {0.f, 0.f}, a11 = {0.f, 0.f};
            // Row 1 dots.
            f32x2 c00 = {0.f, 0.f}, c01 = {0.f, 0.f};
            f32x2 c10 = {0.f, 0.f}, c11 = {0.f, 0.f};
#pragma unroll
            for (int c = 0; c < 4; ++c) {
                const f32x2 lo0 = VLO(e0q[c]), hi0 = VHI(e0q[c]);
                const f32x2 lo1 = VLO(e1q[c]), hi1 = VHI(e1q[c]);
                a00 = pk_fma(lo0, P0[2 * c],     a00);
                a01 = pk_fma(hi0, P0[2 * c + 1], a01);
                a10 = pk_fma(lo1, P0[2 * c],     a10);
                a11 = pk_fma(hi1, P0[2 * c + 1], a11);
                c00 = pk_fma(lo0, P1[2 * c],     c00);
                c01 = pk_fma(hi0, P1[2 * c + 1], c01);
                c10 = pk_fma(lo1, P1[2 * c],     c10);
                c11 = pk_fma(hi1, P1[2 * c + 1], c11);
            }
            const f32x2 r0x0 = pk_add(a00, a01);
            const f32x2 r0x1 = pk_add(a10, a11);
            const f32x2 r1x0 = pk_add(c00, c01);
            const f32x2 r1x1 = pk_add(c10, c11);
            const float X00 = read63(wave_sum63(r0x0.x + r0x0.y));
            const float X01 = read63(wave_sum63(r0x1.x + r0x1.y));
            const float X10 = read63(wave_sum63(r1x0.x + r1x0.y));
            const float X11 = read63(wave_sum63(r1x1.x + r1x1.y));

            // Collect: row0 step k -> lane k; row1 step k -> lane 8+k.
            const bool isk0 = (lane == k);
            const bool isk1 = (lane == k + 8);
            collA = isk0 ? X00 : (isk1 ? X10 : collA);
            collB = isk0 ? X01 : (isk1 ? X11 : collB);

            const int ki0 = (k == 0) ? sA0.x : (k == 1) ? sA0.y
                          : (k == 2) ? sA0.z : (k == 3) ? sA0.w
                          : (k == 4) ? sB0.x : (k == 5) ? sB0.y
                          : (k == 6) ? sB0.z : sB0.w;
            const int ki1 = (k == 0) ? sA1.x : (k == 1) ? sA1.y
                          : (k == 2) ? sA1.z : (k == 3) ? sA1.w
                          : (k == 4) ? sB1.x : (k == 5) ? sB1.y
                          : (k == 6) ? sB1.z : sB1.w;
            const int s0 = __builtin_amdgcn_readfirstlane(ki0);
            const int s1 = __builtin_amdgcn_readfirstlane(ki1);
            smask0 |= (s0 << k);
            smask1 |= (s1 << k);

            // P updates under wave-uniform scalar branches.
            if (s0) {
#pragma unroll
                for (int c = 0; c < 4; ++c) {
                    P0[2 * c]     = pk_mul(P0[2 * c],     VLO(e1q[c]));
                    P0[2 * c + 1] = pk_mul(P0[2 * c + 1], VHI(e1q[c]));
                }
            } else {
#pragma unroll
                for (int c = 0; c < 4; ++c) {
                    P0[2 * c]     = pk_mul(P0[2 * c],     VLO(e0q[c]));
                    P0[2 * c + 1] = pk_mul(P0[2 * c + 1], VHI(e0q[c]));
                }
            }
            if (s1) {
#pragma unroll
                for (int c = 0; c < 4; ++c) {
                    P1[2 * c]     = pk_mul(P1[2 * c],     VLO(e1q[c]));
                    P1[2 * c + 1] = pk_mul(P1[2 * c + 1], VHI(e1q[c]));
                }
            } else {
#pragma unroll
                for (int c = 0; c < 4; ++c) {
                    P1[2 * c]     = pk_mul(P1[2 * c],     VLO(e0q[c]));
                    P1[2 * c + 1] = pk_mul(P1[2 * c + 1], VHI(e0q[c]));
                }
            }

            // Commit staged slice i+1 into the other buffer; barrier gates
            // both "stage complete" and "all reads of cur^1 done".
            *(f32x4*)(&sbuf[cur ^ 1][tid * 4]) = stg;
            __syncthreads();
        }

        // Batched tail: lane k -> row0 step i0+k; lane 8+k -> row1 step i0+k.
        {
            const float Av = collA, Bv = collB;
            const int   kk = lane & 7;
            const int   sm = (lane < 8) ? smask0 : smask1;
            const int   sb = (sm >> kk) & 1;
            const float xs = sb ? Bv : Av;
            const float m  = fmaxf(Av, Bv);
            const float d  = fabsf(Av - Bv);
            const float c  = (xs - m) - 0.5f * __logf(1.0f + __expf(-2.0f * d));
            vacc += (lane < 16) ? c : 0.0f;
        }

        // Block-wide all-|P|-zero vote once per 8 steps.
        float mx = 0.f;
#pragma unroll
        for (int c = 0; c < 8; ++c) {
            mx = fmaxf(mx, fmaxf(fabsf(P0[c].x), fabsf(P0[c].y)));
            mx = fmaxf(mx, fmaxf(fabsf(P1[c].x), fabsf(P1[c].y)));
        }
        if (!__syncthreads_or(mx > 0.0f)) {
            uacc = (float)(L_DIM - 8 - i0) * NEG_HALF_LOG2;
            break;
        }
    }

    // Per-row sums: butterfly within each 8-lane group (xor 1,2,4).
    float s = vacc;
    s += __shfl_xor(s, 1, 64);
    s += __shfl_xor(s, 2, 64);
    s += __shfl_xor(s, 4, 64);
    if (lane == 0) out[b0] = s + uacc;
    if (lane == 8) out[b1] = s + uacc;
}

// ---------------------------------------------------------------------------
// Fallback (no workspace): round-7 per-wave kernel reading eps strided.
// ---------------------------------------------------------------------------
__global__ __launch_bounds__(512, 2) void arqgps_fallback(
    const int* __restrict__ indices,
    const float* __restrict__ eps,    // (2, N, L)
    float* __restrict__ out)
{
    const int lane  = threadIdx.x & 63;
    const int wave  = __builtin_amdgcn_readfirstlane((int)(threadIdx.x >> 6));
    const int b0    = (blockIdx.x * 8 + wave) * 2;
    const int b1    = b0 + 1;
    const int lane4 = lane * 4;
    const int* idx0 = indices + (size_t)b0 * L_DIM;
    const int* idx1 = indices + (size_t)b1 * L_DIM;

    f32x2 P0[8], P1[8];
#pragma unroll
    for (int c = 0; c < 8; ++c) {
        P0[c] = (f32x2){1.0f, 1.0f};
        P1[c] = (f32x2){1.0f, 1.0f};
    }
    float vacc = 0.0f, uacc = 0.0f, collA = 0.0f, collB = 0.0f;

    for (int i0 = 0; i0 < L_DIM; i0 += 8) {
        const int4 sA0 = *(const int4*)(idx0 + i0);
        const int4 sB0 = *(const int4*)(idx0 + i0 + 4);
        const int4 sA1 = *(const int4*)(idx1 + i0);
        const int4 sB1 = *(const int4*)(idx1 + i0 + 4);
        int smask0 = 0, smask1 = 0;
#pragma unroll
        for (int k = 0; k < 8; ++k) {
            const int i = i0 + k;
            f32x4 e0q[4], e1q[4];
#pragma unroll
            for (int c = 0; c < 4; ++c) {
                const int n = c * 256 + lane4;
                f32x4 t0, t1;
#pragma unroll
                for (int j = 0; j < 4; ++j) {
                    t0[j] = eps[(size_t)(n + j) * L_DIM + i];
                    t1[j] = eps[((size_t)N_DIM + n + j) * L_DIM + i];
                }
                e0q[c] = t0; e1q[c] = t1;
            }
            f32x2 a00 = {0.f, 0.f}, a01 = {0.f, 0.f};
            f32x2 a10 = {0.f, 0.f}, a11 = {0.f, 0.f};
            f32x2 c00 = {0.f, 0.f}, c01 = {0.f, 0.f};
            f32x2 c10 = {0.f, 0.f}, c11 = {0.f, 0.f};
#pragma unroll
            for (int c = 0; c < 4; ++c) {
                const f32x2 lo0 = VLO(e0q[c]), hi0 = VHI(e0q[c]);
                const f32x2 lo1 = VLO(e1q[c]), hi1 = VHI(e1q[c]);
                a00 = pk_fma(lo0, P0[2 * c],     a00);
                a01 = pk_fma(hi0, P0[2 * c + 1], a01);
                a10 = pk_fma(lo1, P0[2 * c],     a10);
                a11 = pk_fma(hi1, P0[2 * c + 1], a11);
                c00 = pk_fma(lo0, P1[2 * c],     c00);
                c01 = pk_fma(hi0, P1[2 * c + 1], c01);
                c10 = pk_fma(lo1, P1[2 * c],     c10);
                c11 = pk_fma(hi1, P1[2 * c + 1], c11);
            }
            const f32x2 r0x0 = pk_add(a00, a01);
            const f32x2 r0x1 = pk_add(a10, a11);
            const f32x2 r1x0 = pk_add(c00, c01);
            const f32x2 r1x1 = pk_add(c10, c11);
            const float X00 = read63(wave_sum63(r0x0.x + r0x0.y));
            const float X01 = read63(wave_sum63(r0x1.x + r0x1.y));
            const float X10 = read63(wave_sum63(r1x0.x + r1x0.y));
            const float X11 = read63(wave_sum63(r1x1.x + r1x1.y));
            const bool isk0 = (lane == k);
            const bool isk1 = (lane == k + 8);
            collA = isk0 ? X00 : (isk1 ? X10 : collA);
            collB = isk0 ? X01 : (isk1 ? X11 : collB);
            const int ki0 = (k == 0) ? sA0.x : (k == 1) ? sA0.y
                          : (k == 2) ? sA0.z : (k == 3) ? sA0.w
                          : (k == 4) ? sB0.x : (k == 5) ? sB0.y
                          : (k == 6) ? sB0.z : sB0.w;
            const int ki1 = (k == 0) ? sA1.x : (k == 1) ? sA1.y
                          : (k == 2) ? sA1.z : (k == 3) ? sA1.w
                          : (k == 4) ? sB1.x : (k == 5) ? sB1.y
                          : (k == 6) ? sB1.z : sB1.w;
            const int s0 = __builtin_amdgcn_readfirstlane(ki0);
            const int s1 = __builtin_amdgcn_readfirstlane(ki1);
            smask0 |= (s0 << k);
            smask1 |= (s1 << k);
            if (s0) {
#pragma unroll
                for (int c = 0; c < 4; ++c) {
                    P0[2 * c]     = pk_mul(P0[2 * c],     VLO(e1q[c]));
                    P0[2 * c + 1] = pk_mul(P0[2 * c + 1], VHI(e1q[c]));
                }
            } else {
#pragma unroll
                for (int c = 0; c < 4; ++c) {
                    P0[2 * c]     = pk_mul(P0[2 * c],     VLO(e0q[c]));
                    P0[2 * c + 1] = pk_mul(P0[2 * c + 1], VHI(e0q[c]));
                }
            }
            if (s1) {
#pragma unroll
                for (int c = 0; c < 4; ++c) {
                    P1[2 * c]     = pk_mul(P1[2 * c],     VLO(e1q[c]));
                    P1[2 * c + 1] = pk_mul(P1[2 * c + 1], VHI(e1q[c]));
                }
            } else {
#pragma unroll
                for (int c = 0; c < 4; ++c) {
                    P1[2 * c]     = pk_mul(P1[2 * c],     VLO(e0q[c]));
                    P1[2 * c + 1] = pk_mul(P1[2 * c + 1], VHI(e0q[c]));
                }
            }
        }
        {
            const float Av = collA, Bv = collB;
            const int   kk = lane & 7;
            const int   sm = (lane < 8) ? smask0 : smask1;
            const int   sb = (sm >> kk) & 1;
            const float xs = sb ? Bv : Av;
            const float m  = fmaxf(Av, Bv);
            const float d  = fabsf(Av - Bv);
            const float c  = (xs - m) - 0.5f * __logf(1.0f + __expf(-2.0f * d));
            vacc += (lane < 16) ? c : 0.0f;
        }
        float mx = 0.f;
#pragma unroll
        for (int c = 0; c < 8; ++c) {
            mx = fmaxf(mx, fmaxf(fabsf(P0[c].x), fabsf(P0[c].y)));
            mx = fmaxf(mx, fmaxf(fabsf(P1[c].x), fabsf(P1[c].y)));
        }
        if (!__any(mx > 0.0f)) {
            uacc = (float)(L_DIM - 8 - i0) * NEG_HALF_LOG2;
            break;
        }
    }
    float s = vacc;
    s += __shfl_xor(s, 1, 64);
    s += __shfl_xor(s, 2, 64);
    s += __shfl_xor(s, 4, 64);
    if (lane == 0) out[b0] = s + uacc;
    if (lane == 8) out[b1] = s + uacc;
}

extern "C" void kernel_launch(void* const* d_in, const int* in_sizes, int n_in,
                              void* d_out, int out_size, void* d_ws, size_t ws_size,
                              hipStream_t stream) {
    const int*   indices = (const int*)d_in[0];
    const float* eps     = (const float*)d_in[1];
    float*       out     = (float*)d_out;

    const size_t need = (size_t)2 * N_DIM * L_DIM * sizeof(float);  // 4 MB
    if (ws_size >= need) {
        float* epsT = (float*)d_ws;
        dim3 tgrid(L_DIM / 32, N_DIM / 32, 2);
        transpose_eps<<<tgrid, dim3(32, 8), 0, stream>>>(eps, epsT);
        arqgps_lds<<<B_DIM / 16, 512, 0, stream>>>(indices, epsT, out);
    } else {
        arqgps_fallback<<<B_DIM / 16, 512, 0, stream>>>(indices, eps, out);
    }
}